// Round 8
// baseline (164.287 us; speedup 1.0000x reference)
//
#include <hip/hip_runtime.h>
#include <hip/hip_bf16.h>
#include <cstdint>
#include <cstddef>

// B=8192, CIN=16, 6x6->5x5 (k=2 VALID), FM=64, DK=DV=NH=32 (dkh=1), HID=128, OUT=5.
// R24 = R23 phase-A (spill-free, bpermute k/v, rolled z) with SMALL BLOCKS:
// 256 threads (4 waves), 8 batches/block, grid 1024. LDS 39552 B/block ->
// up to 4 blocks/CU; occupancy granule drops 8->4 waves so the register file
// (VGPR 112 + AGPRs > 128 total) no longer pins us to 1 block/CU.
//  Evidence: R22 (VGPR=64, same 79KB LDS) got 36% occupancy; R23 (VGPR=112) got
//  21% -> the 8-wave block couldn't double up. Corrected rate math: R16 k1 at
//  high occupancy = 1.39 us/batch/CU vs kf 2.0 -> occupancy buys ~1.5x here.
//  Dense reshaped M=8 (row clamp l15&7, write rows<8; layer1 2 col-tiles/wave).
// LDS: act 8*3216=25728 + 4*3456=13824 -> 39552; C1s/C2s reuse scratch after barrier.

typedef __attribute__((ext_vector_type(4))) float f32x4;
typedef __attribute__((ext_vector_type(2))) float f32x2;
typedef __attribute__((ext_vector_type(8))) __bf16 bf16x8;
typedef __attribute__((ext_vector_type(4))) __bf16 bf16x4;

#define LOG2E 1.4426950408889634f
#define ACT_STRIDE 1608                        // elems (bf16); 3216 B/row, 2-way banks
#define ACT_LDS_BYTES (8 * ACT_STRIDE * 2)     // 25728
#define SCRATCH_PER_WAVE 3456                  // qs 1792 + (xs 1152 | as_ 1600 aliased)
#define LDS_TOTAL (ACT_LDS_BYTES + 4 * SCRATCH_PER_WAVE)  // 39552 -> 4 blocks/CU by LDS

// raw v_exp_f32 (2^x) — exp2f() lowers to the OCML wrapper (~4 extra VALU ops).
__device__ __forceinline__ float fast_exp2(float x) {
#if __has_builtin(__builtin_amdgcn_exp2f)
  return __builtin_amdgcn_exp2f(x);
#else
  return __expf(x * 0.6931471805599453f);
#endif
}

// v_mfma_f32_16x16x32_bf16 (bench-verified layout R2-R23):
// A: lane holds A[m=lane&15][k=quad*8+j]; B: W[n=lane&15][k=quad*8+j];
// C/D: col=lane&15, row=quad*4+reg.
__device__ __forceinline__ f32x4 mfma16(bf16x8 a, bf16x8 b, f32x4 c) {
  return __builtin_amdgcn_mfma_f32_16x16x32_bf16(a, b, c, 0, 0, 0);
}

// pack two bf16 (lo,hi) into one dword for bpermute transport (same RNE as before)
__device__ __forceinline__ unsigned pack2(float lo, float hi) {
  unsigned short a = __builtin_bit_cast(unsigned short, __float2bfloat16(lo));
  unsigned short b = __builtin_bit_cast(unsigned short, __float2bfloat16(hi));
  return ((unsigned)b << 16) | (unsigned)a;
}

// select lo/hi bf16 from bpermute result as f32: lsh=16 picks lo, lsh=0 picks hi
__device__ __forceinline__ float bsel(int u, unsigned lsh) {
  return __builtin_bit_cast(float, (((unsigned)u) << lsh) & 0xffff0000u);
}

// ---------------- prep: EVERYTHING kf reads (147 tiny parallel blocks) ----------------
__global__ __launch_bounds__(64) void prep(
    const float* __restrict__ conv_w, const float* __restrict__ conv_b,
    const float* __restrict__ qkv_w,  const float* __restrict__ qkv_b,
    const float* __restrict__ attn_w,
    const float* __restrict__ w1, const float* __restrict__ w2,
    __hip_bfloat16* __restrict__ wqb, float* __restrict__ biasb,
    __hip_bfloat16* __restrict__ wab,
    __hip_bfloat16* __restrict__ w1bp, __hip_bfloat16* __restrict__ w2b) {
  const int t = threadIdx.x, tb = blockIdx.x;
  if (tb < 16) {
#pragma unroll
    for (int j = 0; j < 8; ++j) {
      int i = tb * 512 + j * 64 + t;
      float w = (i < 2048) ? conv_w[i] : qkv_w[i - 2048];
      if (i >= 4096 && i < 6144) w *= LOG2E;  // k-channel rows 64..95
      wqb[i] = __float2bfloat16(w);
    }
  } else if (tb == 16) {
#pragma unroll
    for (int j = 0; j < 16; ++j) wab[j * 64 + t] = __float2bfloat16(attn_w[j * 64 + t]);
    for (int i = t; i < 128; i += 64) {
      float b = (i < 32) ? conv_b[i] : qkv_b[i - 32];
      if (i >= 64 && i < 96) b *= LOG2E;
      biasb[i] = b;
    }
  } else if (tb < 145) {
    // w1bp row u: coalesced fp32 read -> LDS -> coalesced permuted bf16 write.
    const int u = tb - 17;
    __shared__ float rowf[1600];
    const float* wr = w1 + u * 1600;
#pragma unroll
    for (int j = 0; j < 25; ++j) rowf[j * 64 + t] = wr[j * 64 + t];
    __hip_bfloat16* wo = w1bp + u * 1600;
#pragma unroll
    for (int j = 0; j < 25; ++j) {
      // read lds[t*25+j]: stride-25 dwords, gcd(25,32)=1 -> conflict-free
      wo[j * 64 + t] = __float2bfloat16(rowf[t * 25 + j]);
    }
  } else {  // tb = 145,146: w2b cast, 4096 elems each
#pragma unroll
    for (int j = 0; j < 64; ++j) {
      int i = (tb - 145) * 4096 + j * 64 + t;
      w2b[i] = __float2bfloat16(w2[i]);
    }
  }
}

// ---------------- kf: fused conv+qkv GEMM + attention + 1x1 conv + dense ----------------
__global__ __launch_bounds__(256) void kf(
    const float* __restrict__ x,
    const float* __restrict__ biasb,
    const __hip_bfloat16* __restrict__ wqb,
    const __hip_bfloat16* __restrict__ wab, const float* __restrict__ attn_b,
    const __hip_bfloat16* __restrict__ w1bp, const float* __restrict__ b1,
    const __hip_bfloat16* __restrict__ w2b, const float* __restrict__ b2,
    const float* __restrict__ w3, const float* __restrict__ b3,
    float* __restrict__ out) {
  extern __shared__ __align__(16) char lds_all[];
  const int t = threadIdx.x & 63;   // lane within wave
  const int wv = threadIdx.x >> 6;  // wave 0..3
  const int l15 = t & 15, quad = t >> 4;

  __hip_bfloat16* act_lds = (__hip_bfloat16*)lds_all;   // [8][ACT_STRIDE]
  char* my = lds_all + ACT_LDS_BYTES + wv * SCRATCH_PER_WAVE;
  __bf16* qs  = (__bf16*)my;          // q rows 0..31, stride 28 (1792 B)
  __bf16* xs  = (__bf16*)(my + 1792); // 576 elems (1152 B)
  __bf16* as_ = (__bf16*)(my + 1792); // 25x32 (1600 B) — aliases xs (xs dead by then)

  const int b_base = blockIdx.x * 8 + wv * 2;
  const int n = t & 31, half = t >> 5;
  const int i0 = half * 12;
  const int bp0 = (n & 15) * 4;               // bpermute byte base (src lane l15=n&15)
  const unsigned lsh = (n & 16) ? 0u : 16u;   // hi channel half -> take hi16

  // ---- x prefetch for first batch ----
  float xr[9];
  {
    const float* xb = x + (size_t)b_base * 576;
#pragma unroll
    for (int i = 0; i < 9; ++i) xr[i] = xb[t + i * 64];
  }

#pragma unroll 1
  for (int it = 0; it < 2; ++it) {
    const int rowoff = (wv * 2 + it) * ACT_STRIDE;

    // ---- stage x -> bf16 LDS (same-wave LDS ordering; no barrier) ----
#pragma unroll
    for (int i = 0; i < 9; ++i) xs[t + i * 64] = __float2bfloat16(xr[i]);

    // ---- phase 1: mt-outer / nh-inner (peak live ~90 regs; wqb reloads L1-hot) ----
    unsigned pkK[2][4], pkV[2][4];
#pragma unroll
    for (int mt = 0; mt < 2; ++mt) {
      // gather A-frags for this m-tile (8 regs)
      bf16x8 af[2];
      {
        int row = mt * 16 + l15;
        int pos = row < 24 ? row : 24;
        int ii = pos / 5, jj = pos - ii * 5;
        const __bf16* xp = xs + ii * 6 + jj;
#pragma unroll
        for (int ks = 0; ks < 2; ++ks) {
          const __bf16* p0 = xp + (ks * 8 + quad * 2) * 36;
          bf16x8 a;
          a[0] = p0[0];  a[1] = p0[1];  a[2] = p0[6];  a[3] = p0[7];
          a[4] = p0[36]; a[5] = p0[37]; a[6] = p0[42]; a[7] = p0[43];
          af[ks] = a;
        }
      }
#pragma unroll
      for (int nh = 0; nh < 2; ++nh) {
        bf16x8 bf4[4][2];
#pragma unroll
        for (int nt4 = 0; nt4 < 4; ++nt4)
#pragma unroll
          for (int ks = 0; ks < 2; ++ks)
            bf4[nt4][ks] = *(const bf16x8*)((const __bf16*)wqb +
                            ((nh * 4 + nt4) * 16 + l15) * 64 + ks * 32 + quad * 8);
        float bs[4];
#pragma unroll
        for (int nt4 = 0; nt4 < 4; ++nt4) bs[nt4] = biasb[(nh * 4 + nt4) * 16 + l15];

        f32x4 acc[4];
#pragma unroll
        for (int nt4 = 0; nt4 < 4; ++nt4) acc[nt4] = (f32x4){0.f, 0.f, 0.f, 0.f};
#pragma unroll
        for (int ks = 0; ks < 2; ++ks)
#pragma unroll
          for (int nt4 = 0; nt4 < 4; ++nt4)
            acc[nt4] = mfma16(af[ks], bf4[nt4][ks], acc[nt4]);

        if (nh == 0) {
          // conv ch 0..31 -> act LDS (relu); q ch 0..31 -> qs rows (stride 28)
#pragma unroll
          for (int r = 0; r < 4; ++r) {
            int orow = mt * 16 + quad * 4 + r;
            if (orow < 25) {
              act_lds[rowoff + orow * 64 + 0 * 16 + l15] =
                  __float2bfloat16(fmaxf(acc[0][r] + bs[0], 0.f));
              act_lds[rowoff + orow * 64 + 1 * 16 + l15] =
                  __float2bfloat16(fmaxf(acc[1][r] + bs[1], 0.f));
              qs[(0 * 16 + l15) * 28 + orow] = __float2bfloat16(acc[2][r] + bs[2]);
              qs[(1 * 16 + l15) * 28 + orow] = __float2bfloat16(acc[3][r] + bs[3]);
            }
          }
        } else {
          // k/v: packed for bpermute transpose (garbage beyond pos 24 never read)
#pragma unroll
          for (int r = 0; r < 4; ++r) {
            pkK[mt][r] = pack2(acc[0][r] + bs[0], acc[1][r] + bs[1]);
            pkV[mt][r] = pack2(acc[2][r] + bs[2], acc[3][r] + bs[3]);
          }
        }
      }
    }

    // ---- issue next batch's x loads (lands under attention compute) ----
    if (it == 0) {
      const float* xb = x + (size_t)(b_base + 1) * 576;
#pragma unroll
      for (int i = 0; i < 9; ++i) xr[i] = xb[t + i * 64];
    }

    // ---- k/v transpose via ds_bpermute: lane n pulls k[32+n][j], v[64+n][j] ----
    f32x2 kl2[12], vv2[12];
#pragma unroll
    for (int c = 0; c < 12; ++c) {
      const int j0 = 2 * c, j1 = 2 * c + 1;
      int uk0 = __builtin_amdgcn_ds_bpermute(bp0 + 64 * ((j0 >> 2) & 3), (int)pkK[j0 >> 4][j0 & 3]);
      int uk1 = __builtin_amdgcn_ds_bpermute(bp0 + 64 * ((j1 >> 2) & 3), (int)pkK[j1 >> 4][j1 & 3]);
      int uv0 = __builtin_amdgcn_ds_bpermute(bp0 + 64 * ((j0 >> 2) & 3), (int)pkV[j0 >> 4][j0 & 3]);
      int uv1 = __builtin_amdgcn_ds_bpermute(bp0 + 64 * ((j1 >> 2) & 3), (int)pkV[j1 >> 4][j1 & 3]);
      kl2[c] = (f32x2){bsel(uk0, lsh), bsel(uk1, lsh)};
      vv2[c] = (f32x2){bsel(uv0, lsh), bsel(uv1, lsh)};
    }
    const float kl24 = bsel(__builtin_amdgcn_ds_bpermute(bp0 + 128, (int)pkK[1][0]), lsh);
    const float vv24 = bsel(__builtin_amdgcn_ds_bpermute(bp0 + 128, (int)pkV[1][0]), lsh);

    // ---- phase 2: attention (rolled z, q streamed from LDS, packed-fp32 body) ----
    {
      const __bf16* qp = qs + n * 28 + i0;
      float qcur = (float)qp[0];
#pragma unroll 1
      for (int z = 0; z < 13; ++z) {
        const float qi = qcur;
        qcur = (float)qp[z + 1];  // prefetch next q (z=12 reads in-row pad; unused)
        const f32x2 qi2 = {qi, qi};
        f32x2 sA = {0.f, 0.f}, sB = {0.f, 0.f};
        f32x2 oA = {0.f, 0.f}, oB = {0.f, 0.f};
        float s4 = 0.f, o4 = 0.f;
#pragma unroll
        for (int p = 0; p < 6; ++p) {
          f32x2 mA = qi2 * kl2[p];          // v_pk_mul_f32
          f32x2 mB = qi2 * kl2[p + 6];
          f32x2 eA = {fast_exp2(mA.x), fast_exp2(mA.y)};
          f32x2 eB = {fast_exp2(mB.x), fast_exp2(mB.y)};
          sA += eA;                          // v_pk_add_f32
          sB += eB;
          oA = eA * vv2[p] + oA;             // v_pk_fma_f32
          oB = eB * vv2[p + 6] + oB;
        }
        {
          float e = fast_exp2(qi * kl24);
          s4 += e;
          o4 = __builtin_fmaf(e, vv24, o4);
        }
        float ss = ((sA.x + sA.y) + (sB.x + sB.y)) + s4;
        float oo = ((oA.x + oA.y) + (oB.x + oB.y)) + o4;
        as_[(i0 + z) * 32 + n] = __float2bfloat16(oo * __builtin_amdgcn_rcpf(ss));
      }
    }

    // ---- phase 3: 1x1 conv via MFMA. M=25 rows, K=32 heads, N=32 ----
    {
      bf16x8 bw[2]; float ab[2];  // loaded here (L2-hot) to keep phase-1 pressure low
#pragma unroll
      for (int nt2 = 0; nt2 < 2; ++nt2) {
        int nn = nt2 * 16 + l15;
        bw[nt2] = *(const bf16x8*)((const __bf16*)wab + nn * 32 + quad * 8);
        ab[nt2] = attn_b[nn];
      }
#pragma unroll
      for (int mt = 0; mt < 2; ++mt) {
        int row = mt * 16 + l15;
        int rc = row < 24 ? row : 24;
        bf16x8 af = *(const bf16x8*)(as_ + rc * 32 + quad * 8);
        f32x4 acc[2];
#pragma unroll
        for (int nt2 = 0; nt2 < 2; ++nt2)
          acc[nt2] = mfma16(af, bw[nt2], (f32x4){0.f, 0.f, 0.f, 0.f});
#pragma unroll
        for (int r = 0; r < 4; ++r) {
          int orow = mt * 16 + quad * 4 + r;
          if (orow < 25) {
#pragma unroll
            for (int nt2 = 0; nt2 < 2; ++nt2)
              act_lds[rowoff + orow * 64 + 32 + nt2 * 16 + l15] =
                  __float2bfloat16(fmaxf(acc[nt2][r] + ab[nt2], 0.f));
          }
        }
      }
    }
  }  // batch loop

  __syncthreads();

  // ================= dense chain, M=8 (A rows = block's 8 batches, LDS) =================
  // A-row index clamped (l15&7) to stay inside the 8-row act tile; C rows 8..15
  // are duplicates of 0..7 and never written.
  const int wave = threadIdx.x >> 6;  // 0..3
  const int b0 = blockIdx.x * 8;
  const int arow = l15 & 7;

  __hip_bfloat16* C1s = (__hip_bfloat16*)(lds_all + ACT_LDS_BYTES);         // 8*136*2 = 2176 B
  __hip_bfloat16* C2s = (__hip_bfloat16*)(lds_all + ACT_LDS_BYTES + 2176);  // 8*72*2 = 1152 B

  // ---- layer 1: [8,1600](LDS) x [128,1600]^T; wave w -> cols w*32..w*32+31 ----
  {
    f32x4 acc[2][2];
#pragma unroll
    for (int ct = 0; ct < 2; ++ct)
#pragma unroll
      for (int ks = 0; ks < 2; ++ks) acc[ct][ks] = (f32x4){0.f, 0.f, 0.f, 0.f};
    const __bf16* aL    = (const __bf16*)act_lds + arow * ACT_STRIDE + quad * 8;
    const __bf16* bptr0 = (const __bf16*)w1bp + (size_t)(wave * 32 + l15) * 1600 + quad * 8;
    const __bf16* bptr1 = bptr0 + 16 * 1600;
#pragma unroll 5
    for (int k0 = 0; k0 < 1600; k0 += 64) {
      bf16x8 av0 = *(const bf16x8*)(aL + k0);
      bf16x8 av1 = *(const bf16x8*)(aL + k0 + 32);
      acc[0][0] = mfma16(av0, *(const bf16x8*)(bptr0 + k0),      acc[0][0]);
      acc[0][1] = mfma16(av1, *(const bf16x8*)(bptr0 + k0 + 32), acc[0][1]);
      acc[1][0] = mfma16(av0, *(const bf16x8*)(bptr1 + k0),      acc[1][0]);
      acc[1][1] = mfma16(av1, *(const bf16x8*)(bptr1 + k0 + 32), acc[1][1]);
    }
#pragma unroll
    for (int ct = 0; ct < 2; ++ct) {
      const int col = wave * 32 + ct * 16 + l15;
      const float bias1 = b1[col];
#pragma unroll
      for (int r = 0; r < 4; ++r) {
        const int row = quad * 4 + r;
        if (row < 8)
          C1s[row * 136 + col] =
              __float2bfloat16(fmaxf(acc[ct][0][r] + acc[ct][1][r] + bias1, 0.f));
      }
    }
  }
  __syncthreads();

  // ---- layer 2: [8,128] x [64,128]^T; wave w -> cols w*16..w*16+15 ----
  {
    f32x4 acc2 = {0.f, 0.f, 0.f, 0.f};
    const __bf16* aL = (const __bf16*)C1s + arow * 136 + quad * 8;
    const __bf16* bL = (const __bf16*)w2b + (wave * 16 + l15) * 128 + quad * 8;
#pragma unroll
    for (int k0 = 0; k0 < 128; k0 += 32)
      acc2 = mfma16(*(const bf16x8*)(aL + k0), *(const bf16x8*)(bL + k0), acc2);
    const int col = wave * 16 + l15;
    const float bias = b2[col];
#pragma unroll
    for (int r = 0; r < 4; ++r) {
      const int row = quad * 4 + r;
      if (row < 8)
        C2s[row * 72 + col] = __float2bfloat16(fmaxf(acc2[r] + bias, 0.f));
    }
  }
  __syncthreads();

  // ---- layer 3 (scalar, 40 outputs) ----
  if (threadIdx.x < 40) {
    const int row = threadIdx.x / 5;
    const int oc = threadIdx.x - row * 5;
    float s = b3[oc];
#pragma unroll
    for (int k = 0; k < 64; ++k)
      s += __bfloat162float(C2s[row * 72 + k]) * w3[oc * 64 + k];
    out[(size_t)(b0 + row) * 5 + oc] = s;
  }
}

extern "C" void kernel_launch(void* const* d_in, const int* in_sizes, int n_in,
                              void* d_out, int out_size, void* d_ws, size_t ws_size,
                              hipStream_t stream) {
  const float* x      = (const float*)d_in[0];
  const float* conv_w = (const float*)d_in[1];
  const float* conv_b = (const float*)d_in[2];
  const float* qkv_w  = (const float*)d_in[3];
  const float* qkv_b  = (const float*)d_in[4];
  const float* attn_w = (const float*)d_in[5];
  const float* attn_b = (const float*)d_in[6];
  const float* w1 = (const float*)d_in[7];
  const float* b1 = (const float*)d_in[8];
  const float* w2 = (const float*)d_in[9];
  const float* b2 = (const float*)d_in[10];
  const float* w3 = (const float*)d_in[11];
  const float* b3 = (const float*)d_in[12];
  float* out = (float*)d_out;

  // workspace layout (16B-aligned):
  //   w1bp  [128][1600] bf16 : 409,600 B  (K pre-permuted to [pos][ch])
  //   w2b   [64][128]   bf16 :  16,384 B
  //   wqb   [128][64]   bf16 :  16,384 B  (k rows pre-scaled by log2e)
  //   biasb [128]       f32  :     512 B  (k entries pre-scaled by log2e)
  //   wab   [32][32]    bf16 :   2,048 B
  char* ws = (char*)d_ws;
  __hip_bfloat16* w1bp  = (__hip_bfloat16*)ws;
  __hip_bfloat16* w2b   = (__hip_bfloat16*)(ws + 409600);
  __hip_bfloat16* wqb   = (__hip_bfloat16*)(ws + 425984);
  float*          biasb = (float*)(ws + 442368);
  __hip_bfloat16* wab   = (__hip_bfloat16*)(ws + 442880);

  hipFuncSetAttribute(reinterpret_cast<const void*>(kf),
                      hipFuncAttributeMaxDynamicSharedMemorySize, LDS_TOTAL);

  prep<<<dim3(147), dim3(64), 0, stream>>>(conv_w, conv_b, qkv_w, qkv_b, attn_w,
                                           w1, w2, wqb, biasb, wab, w1bp, w2b);
  kf<<<dim3(1024), dim3(256), LDS_TOTAL, stream>>>(x, biasb, wqb, wab, attn_b,
                                                   w1bp, b1, w2b, b2, w3, b3, out);
}

// Round 9
// 147.496 us; speedup vs baseline: 1.1138x; 1.1138x over previous
//
#include <hip/hip_runtime.h>
#include <hip/hip_bf16.h>
#include <cstdint>
#include <cstddef>

// B=8192, CIN=16, 6x6->5x5 (k=2 VALID), FM=64, DK=DV=NH=32 (dkh=1), HID=128, OUT=5.
// R25 = exact R18 revert (session best: 148.25 us total, kf 71.4 us, absmax 0.015625).
// Post-R18 ledger: R19 pipeline null, R20 code-size null, R21/R22 spill disasters
// (forced 128-reg cap splits unified file), R23 156.4, R24 164.3 (occupancy pinned
// at 8 waves/CU by unified VGPR+AGPR >128 -> 256-reg granule; <=128 spills).
// kf: k1+k2 fused (256 blocks x 512 thr, 32 batches/block).
//  - phase A: per-wave barrier-free pipeline (private 7KB scratch, packed-fp32
//    attention, raw v_exp_f32, log2e pre-scaled k), 4 batches/wave sequential,
//    x prefetched into regs one batch ahead; act rows -> LDS [32][1608] bf16
//    (3216B row stride: 16B-aligned, dword-stride 804%32==4 -> 2-way max).
//  - one __syncthreads(), then the R2-proven dense chain with A read from LDS.
// LDS total = 102912 + 8*7168 = 160256 <= 160KiB (dynamic, via FuncSetAttribute).

typedef __attribute__((ext_vector_type(4))) float f32x4;
typedef __attribute__((ext_vector_type(2))) float f32x2;
typedef __attribute__((ext_vector_type(8))) __bf16 bf16x8;
typedef __attribute__((ext_vector_type(4))) __bf16 bf16x4;

#define LOG2E 1.4426950408889634f
#define ACT_STRIDE 1608                        // elems (bf16); 3216 B/row
#define ACT_LDS_BYTES (32 * ACT_STRIDE * 2)    // 102912
#define SCRATCH_OFF ACT_LDS_BYTES
#define LDS_TOTAL (ACT_LDS_BYTES + 8 * 7168)   // 160256

// raw v_exp_f32 (2^x) — exp2f() lowers to the OCML wrapper (~4 extra VALU ops).
__device__ __forceinline__ float fast_exp2(float x) {
#if __has_builtin(__builtin_amdgcn_exp2f)
  return __builtin_amdgcn_exp2f(x);
#else
  return __expf(x * 0.6931471805599453f);
#endif
}

// v_mfma_f32_16x16x32_bf16 (bench-verified layout R2-R24):
// A: lane holds A[m=lane&15][k=quad*8+j]; B: W[n=lane&15][k=quad*8+j];
// C/D: col=lane&15, row=quad*4+reg.
__device__ __forceinline__ f32x4 mfma16(bf16x8 a, bf16x8 b, f32x4 c) {
  return __builtin_amdgcn_mfma_f32_16x16x32_bf16(a, b, c, 0, 0, 0);
}

// ---------------- prep: EVERYTHING kf reads (147 tiny parallel blocks) ----------------
__global__ __launch_bounds__(64) void prep(
    const float* __restrict__ conv_w, const float* __restrict__ conv_b,
    const float* __restrict__ qkv_w,  const float* __restrict__ qkv_b,
    const float* __restrict__ attn_w,
    const float* __restrict__ w1, const float* __restrict__ w2,
    __hip_bfloat16* __restrict__ wqb, float* __restrict__ biasb,
    __hip_bfloat16* __restrict__ wab,
    __hip_bfloat16* __restrict__ w1bp, __hip_bfloat16* __restrict__ w2b) {
  const int t = threadIdx.x, tb = blockIdx.x;
  if (tb < 16) {
#pragma unroll
    for (int j = 0; j < 8; ++j) {
      int i = tb * 512 + j * 64 + t;
      float w = (i < 2048) ? conv_w[i] : qkv_w[i - 2048];
      if (i >= 4096 && i < 6144) w *= LOG2E;  // k-channel rows 64..95
      wqb[i] = __float2bfloat16(w);
    }
  } else if (tb == 16) {
#pragma unroll
    for (int j = 0; j < 16; ++j) wab[j * 64 + t] = __float2bfloat16(attn_w[j * 64 + t]);
    for (int i = t; i < 128; i += 64) {
      float b = (i < 32) ? conv_b[i] : qkv_b[i - 32];
      if (i >= 64 && i < 96) b *= LOG2E;
      biasb[i] = b;
    }
  } else if (tb < 145) {
    // w1bp row u: coalesced fp32 read -> LDS -> coalesced permuted bf16 write.
    // single wave: same-wave LDS RAW ordered by lgkmcnt (no barrier needed)
    const int u = tb - 17;
    __shared__ float rowf[1600];
    const float* wr = w1 + u * 1600;
#pragma unroll
    for (int j = 0; j < 25; ++j) rowf[j * 64 + t] = wr[j * 64 + t];
    __hip_bfloat16* wo = w1bp + u * 1600;
#pragma unroll
    for (int j = 0; j < 25; ++j) {
      // read lds[t*25+j]: stride-25 dwords, gcd(25,32)=1 -> conflict-free
      wo[j * 64 + t] = __float2bfloat16(rowf[t * 25 + j]);
    }
  } else {  // tb = 145,146: w2b cast, 4096 elems each
#pragma unroll
    for (int j = 0; j < 64; ++j) {
      int i = (tb - 145) * 4096 + j * 64 + t;
      w2b[i] = __float2bfloat16(w2[i]);
    }
  }
}

// ---------------- kf: fully fused conv+qkv GEMM + attention + 1x1 conv + dense ----------------
__global__ __launch_bounds__(512) void kf(
    const float* __restrict__ x,
    const float* __restrict__ biasb,
    const __hip_bfloat16* __restrict__ wqb,
    const __hip_bfloat16* __restrict__ wab, const float* __restrict__ attn_b,
    const __hip_bfloat16* __restrict__ w1bp, const float* __restrict__ b1,
    const __hip_bfloat16* __restrict__ w2b, const float* __restrict__ b2,
    const float* __restrict__ w3, const float* __restrict__ b3,
    float* __restrict__ out) {
  extern __shared__ __align__(16) char lds_all[];
  const int t = threadIdx.x & 63;   // lane within wave
  const int wv = threadIdx.x >> 6;  // wave 0..7
  const int l15 = t & 15, quad = t >> 4;

  __hip_bfloat16* act_lds = (__hip_bfloat16*)lds_all;   // [32][ACT_STRIDE]
  char* my = lds_all + SCRATCH_OFF + wv * 7168;         // private per-wave region
  __bf16* xs  = (__bf16*)my;          // phase 1 (576 elems)
  __bf16* as_ = (__bf16*)my;          // phase 2/3 (800 elems, stride 32)
  __bf16* qs  = (__bf16*)(my + 1600); // q:0-31 k:32-63(x log2e) v:64-95, stride 28

  // ---- batch-invariant operand frags (hoisted out of the batch loop) ----
  bf16x8 bfr[8][2];
#pragma unroll
  for (int nt = 0; nt < 8; ++nt)
#pragma unroll
    for (int ks = 0; ks < 2; ++ks)
      bfr[nt][ks] = *(const bf16x8*)((const __bf16*)wqb + (nt * 16 + l15) * 64 + ks * 32 + quad * 8);
  float bias[8];
#pragma unroll
  for (int nt = 0; nt < 8; ++nt) bias[nt] = biasb[nt * 16 + l15];
  bf16x8 bw[2]; float ab[2];
#pragma unroll
  for (int nt2 = 0; nt2 < 2; ++nt2) {
    int n = nt2 * 16 + l15;
    bw[nt2] = *(const bf16x8*)((const __bf16*)wab + n * 32 + quad * 8);
    ab[nt2] = attn_b[n];
  }

  const int b_base = blockIdx.x * 32 + wv * 4;

  // ---- x prefetch for first batch (regs; HBM latency hides under prior work) ----
  float xr[9];
  {
    const float* xb = x + (size_t)b_base * 576;
#pragma unroll
    for (int i = 0; i < 9; ++i) xr[i] = xb[t + i * 64];
  }

  for (int it = 0; it < 4; ++it) {
    const int rowoff = (wv * 4 + it) * ACT_STRIDE;

    // ---- stage x -> bf16 LDS (same-wave LDS ordering; no barrier) ----
#pragma unroll
    for (int i = 0; i < 9; ++i) xs[t + i * 64] = __float2bfloat16(xr[i]);

    // ---- phase 1: implicit GEMM, M=25, N=128, K=64; 2 m-tiles sequential ----
#pragma unroll
    for (int mt = 0; mt < 2; ++mt) {
      int row = mt * 16 + l15;
      int pos = row < 24 ? row : 24;
      int ii = pos / 5, jj = pos - ii * 5;
      const __bf16* xp = xs + ii * 6 + jj;
      bf16x8 af[2];
#pragma unroll
      for (int ks = 0; ks < 2; ++ks) {
        const __bf16* p0 = xp + (ks * 8 + quad * 2) * 36;
        bf16x8 a;
        a[0] = p0[0];  a[1] = p0[1];  a[2] = p0[6];  a[3] = p0[7];
        a[4] = p0[36]; a[5] = p0[37]; a[6] = p0[42]; a[7] = p0[43];
        af[ks] = a;
      }
      f32x4 acc[8];
#pragma unroll
      for (int nt = 0; nt < 8; ++nt) acc[nt] = (f32x4){0.f, 0.f, 0.f, 0.f};
#pragma unroll
      for (int ks = 0; ks < 2; ++ks)
#pragma unroll
        for (int nt = 0; nt < 8; ++nt)
          acc[nt] = mfma16(af[ks], bfr[nt][ks], acc[nt]);

#pragma unroll
      for (int r = 0; r < 4; ++r) {
        int orow = mt * 16 + quad * 4 + r;
        if (orow < 25) {
#pragma unroll
          for (int nt = 0; nt < 8; ++nt) {
            float v = acc[nt][r] + bias[nt];
            if (nt < 2) {  // conv_out ch 0..31 -> act LDS with relu
              act_lds[rowoff + orow * 64 + nt * 16 + l15] =
                  __float2bfloat16(fmaxf(v, 0.f));
            } else {       // qkv ch 0..95 -> LDS (k already log2e-scaled)
              qs[((nt - 2) * 16 + l15) * 28 + orow] = __float2bfloat16(v);
            }
          }
        }
      }
    }

    // ---- prefetch next batch's x (overlaps with phase 2/3 compute) ----
    if (it < 3) {
      const float* xb = x + (size_t)(b_base + it + 1) * 576;
#pragma unroll
      for (int i = 0; i < 9; ++i) xr[i] = xb[t + i * 64];
    }

    // ---- phase 2: attention, dkh=1; e = 2^(q * k*log2e) via raw v_exp_f32.
    //      PACKED inner loop: 4 packed + 1 scalar acc chains. ----
    {
      const int n = t & 31, half = t >> 5;
      const __bf16* qp = qs + n * 28;
      const __bf16* kp = qs + (32 + n) * 28;
      const __bf16* vp = qs + (64 + n) * 28;
      f32x2 kl2[12], vv2[12];
      float kl24, vv24;
#pragma unroll
      for (int c4 = 0; c4 < 6; ++c4) {
        bf16x4 bb = *(const bf16x4*)(kp + c4 * 4);
        bf16x4 cc = *(const bf16x4*)(vp + c4 * 4);
        kl2[c4 * 2]     = (f32x2){(float)bb[0], (float)bb[1]};
        kl2[c4 * 2 + 1] = (f32x2){(float)bb[2], (float)bb[3]};
        vv2[c4 * 2]     = (f32x2){(float)cc[0], (float)cc[1]};
        vv2[c4 * 2 + 1] = (f32x2){(float)cc[2], (float)cc[3]};
      }
      kl24 = (float)kp[24]; vv24 = (float)vp[24];

      const int i0 = half * 12;
      float qv[13];
      {
        const __bf16* qbase = qp + i0;  // 8B-aligned for i0 in {0,12}
        bf16x4 q0 = *(const bf16x4*)(qbase);
        bf16x4 q1 = *(const bf16x4*)(qbase + 4);
        bf16x4 q2 = *(const bf16x4*)(qbase + 8);
#pragma unroll
        for (int z = 0; z < 4; ++z) {
          qv[z] = (float)q0[z]; qv[4 + z] = (float)q1[z]; qv[8 + z] = (float)q2[z];
        }
        qv[12] = (float)qbase[12];
      }

#pragma unroll
      for (int z = 0; z < 13; ++z) {
        const float qi = qv[z];
        const f32x2 qi2 = {qi, qi};
        f32x2 sA = {0.f, 0.f}, sB = {0.f, 0.f};
        f32x2 oA = {0.f, 0.f}, oB = {0.f, 0.f};
        float s4 = 0.f, o4 = 0.f;
#pragma unroll
        for (int p = 0; p < 6; ++p) {
          f32x2 mA = qi2 * kl2[p];          // v_pk_mul_f32
          f32x2 mB = qi2 * kl2[p + 6];
          f32x2 eA = {fast_exp2(mA.x), fast_exp2(mA.y)};
          f32x2 eB = {fast_exp2(mB.x), fast_exp2(mB.y)};
          sA += eA;                          // v_pk_add_f32
          sB += eB;
          oA = eA * vv2[p] + oA;             // v_pk_fma_f32
          oB = eB * vv2[p + 6] + oB;
        }
        {
          float e = fast_exp2(qi * kl24);
          s4 += e;
          o4 = __builtin_fmaf(e, vv24, o4);
        }
        float ss = ((sA.x + sA.y) + (sB.x + sB.y)) + s4;
        float oo = ((oA.x + oA.y) + (oB.x + oB.y)) + o4;
        as_[(i0 + z) * 32 + n] = __float2bfloat16(oo * __builtin_amdgcn_rcpf(ss));
      }
    }

    // ---- phase 3: 1x1 conv via MFMA. M=25 rows, K=32 heads, N=32 ----
    {
#pragma unroll
      for (int mt = 0; mt < 2; ++mt) {
        int row = mt * 16 + l15;
        int rc = row < 24 ? row : 24;
        bf16x8 af = *(const bf16x8*)(as_ + rc * 32 + quad * 8);
        f32x4 acc[2];
#pragma unroll
        for (int nt2 = 0; nt2 < 2; ++nt2)
          acc[nt2] = mfma16(af, bw[nt2], (f32x4){0.f, 0.f, 0.f, 0.f});
#pragma unroll
        for (int r = 0; r < 4; ++r) {
          int orow = mt * 16 + quad * 4 + r;
          if (orow < 25) {
#pragma unroll
            for (int nt2 = 0; nt2 < 2; ++nt2)
              act_lds[rowoff + orow * 64 + 32 + nt2 * 16 + l15] =
                  __float2bfloat16(fmaxf(acc[nt2][r] + ab[nt2], 0.f));
          }
        }
      }
    }
  }  // batch loop

  __syncthreads();

  // ================= dense chain (R2-proven 32-row/2-acc shape, A from LDS) =================
  const int wave = threadIdx.x >> 6;
  const int wm = wave >> 2;  // 0..1
  const int wn = wave & 3;   // 0..3
  const int b0 = blockIdx.x * 32;

  __hip_bfloat16* C1s = (__hip_bfloat16*)(lds_all + SCRATCH_OFF);         // 32*136*2 = 8704 B
  __hip_bfloat16* C2s = (__hip_bfloat16*)(lds_all + SCRATCH_OFF + 8704);  // 32*72*2 = 4608 B

  // ---- layer 1: [32,1600](LDS) x [128,1600]^T ----
  f32x4 acc0 = {0.f, 0.f, 0.f, 0.f};
  f32x4 acc1 = {0.f, 0.f, 0.f, 0.f};
  {
    const __bf16* aL    = (const __bf16*)act_lds + (wm * 16 + l15) * ACT_STRIDE + quad * 8;
    const __bf16* bptr0 = (const __bf16*)w1bp + (size_t)(wn * 32 + l15) * 1600 + quad * 8;
    const __bf16* bptr1 = bptr0 + 16 * 1600;
#pragma unroll 5
    for (int k0 = 0; k0 < 1600; k0 += 32) {
      bf16x8 av  = *(const bf16x8*)(aL + k0);      // ds_read_b128, 2-way max
      bf16x8 bv0 = *(const bf16x8*)(bptr0 + k0);
      bf16x8 bv1 = *(const bf16x8*)(bptr1 + k0);
      acc0 = mfma16(av, bv0, acc0);
      acc1 = mfma16(av, bv1, acc1);
    }
  }
  {
    const int col0 = wn * 32 + l15;
    const float bias0 = b1[col0];
    const float bias1 = b1[col0 + 16];
#pragma unroll
    for (int r = 0; r < 4; ++r) {
      const int row = wm * 16 + quad * 4 + r;
      C1s[row * 136 + col0]      = __float2bfloat16(fmaxf(acc0[r] + bias0, 0.f));
      C1s[row * 136 + col0 + 16] = __float2bfloat16(fmaxf(acc1[r] + bias1, 0.f));
    }
  }
  __syncthreads();

  // ---- layer 2: [32,128] x [64,128]^T ----
  f32x4 acc2 = {0.f, 0.f, 0.f, 0.f};
  {
    const __bf16* aL = (const __bf16*)C1s + (wm * 16 + l15) * 136 + quad * 8;
    const __bf16* bL = (const __bf16*)w2b + (wn * 16 + l15) * 128 + quad * 8;
#pragma unroll
    for (int k0 = 0; k0 < 128; k0 += 32)
      acc2 = mfma16(*(const bf16x8*)(aL + k0), *(const bf16x8*)(bL + k0), acc2);
  }
  {
    const int col = wn * 16 + l15;
    const float bias = b2[col];
#pragma unroll
    for (int r = 0; r < 4; ++r) {
      const int row = wm * 16 + quad * 4 + r;
      C2s[row * 72 + col] = __float2bfloat16(fmaxf(acc2[r] + bias, 0.f));
    }
  }
  __syncthreads();

  // ---- layer 3 (scalar, 160 outputs) ----
  if (threadIdx.x < 160) {
    const int row = threadIdx.x / 5;
    const int oc = threadIdx.x - row * 5;
    float s = b3[oc];
#pragma unroll
    for (int k = 0; k < 64; ++k)
      s += __bfloat162float(C2s[row * 72 + k]) * w3[oc * 64 + k];
    out[(size_t)(b0 + row) * 5 + oc] = s;
  }
}

extern "C" void kernel_launch(void* const* d_in, const int* in_sizes, int n_in,
                              void* d_out, int out_size, void* d_ws, size_t ws_size,
                              hipStream_t stream) {
  const float* x      = (const float*)d_in[0];
  const float* conv_w = (const float*)d_in[1];
  const float* conv_b = (const float*)d_in[2];
  const float* qkv_w  = (const float*)d_in[3];
  const float* qkv_b  = (const float*)d_in[4];
  const float* attn_w = (const float*)d_in[5];
  const float* attn_b = (const float*)d_in[6];
  const float* w1 = (const float*)d_in[7];
  const float* b1 = (const float*)d_in[8];
  const float* w2 = (const float*)d_in[9];
  const float* b2 = (const float*)d_in[10];
  const float* w3 = (const float*)d_in[11];
  const float* b3 = (const float*)d_in[12];
  float* out = (float*)d_out;

  // workspace layout (16B-aligned):
  //   w1bp  [128][1600] bf16 : 409,600 B  (K pre-permuted to [pos][ch])
  //   w2b   [64][128]   bf16 :  16,384 B
  //   wqb   [128][64]   bf16 :  16,384 B  (k rows pre-scaled by log2e)
  //   biasb [128]       f32  :     512 B  (k entries pre-scaled by log2e)
  //   wab   [32][32]    bf16 :   2,048 B
  char* ws = (char*)d_ws;
  __hip_bfloat16* w1bp  = (__hip_bfloat16*)ws;
  __hip_bfloat16* w2b   = (__hip_bfloat16*)(ws + 409600);
  __hip_bfloat16* wqb   = (__hip_bfloat16*)(ws + 425984);
  float*          biasb = (float*)(ws + 442368);
  __hip_bfloat16* wab   = (__hip_bfloat16*)(ws + 442880);

  hipFuncSetAttribute(reinterpret_cast<const void*>(kf),
                      hipFuncAttributeMaxDynamicSharedMemorySize, LDS_TOTAL);

  prep<<<dim3(147), dim3(64), 0, stream>>>(conv_w, conv_b, qkv_w, qkv_b, attn_w,
                                           w1, w2, wqb, biasb, wab, w1bp, w2b);
  kf<<<dim3(256), dim3(512), LDS_TOTAL, stream>>>(x, biasb, wqb, wab, attn_b,
                                                  w1bp, b1, w2b, b2, w3, b3, out);
}